// Round 1
// 312.179 us; speedup vs baseline: 1.1615x; 1.1615x over previous
//
#include <hip/hip_runtime.h>
#include <hip/hip_fp16.h>
#include <math.h>

#define FEAT 128
#define HID  64
#define BSH  7                 // 128 dst-nodes per bucket
#define BNODES (1 << BSH)
#define PB   256               // partition blocks (256: full-chip parallelism — PB=64 regressed 2.5x)
#define SRCM ((1u << 25) - 1)  // src in low 25 bits, dst_local in high 7

// ---------------- stage 1: edge partition by dst-bucket ----------------

__global__ void part_hist_k(const int* __restrict__ dst, int* __restrict__ table,
                            int e, int nb) {
    __shared__ int lcnt[1024];
    for (int i = threadIdx.x; i < nb; i += 256) lcnt[i] = 0;
    __syncthreads();
    int eb = (e + PB - 1) / PB;
    int lo = blockIdx.x * eb, hi = min(lo + eb, e);
    for (int i = lo + threadIdx.x; i < hi; i += 256)
        atomicAdd(&lcnt[dst[i] >> BSH], 1);
    __syncthreads();
    for (int k = threadIdx.x; k < nb; k += 256)
        table[k * PB + blockIdx.x] = lcnt[k];
}

__global__ void scan1_k(int* __restrict__ data, int* __restrict__ aux, int L) {
    __shared__ int s[1024];
    int gid = blockIdx.x * 1024 + threadIdx.x;
    int v = (gid < L) ? data[gid] : 0;
    s[threadIdx.x] = v;
    __syncthreads();
    for (int off = 1; off < 1024; off <<= 1) {
        int t = (threadIdx.x >= off) ? s[threadIdx.x - off] : 0;
        __syncthreads();
        s[threadIdx.x] += t;
        __syncthreads();
    }
    if (gid < L) data[gid] = s[threadIdx.x] - v;            // exclusive in block
    if (threadIdx.x == 1023) aux[blockIdx.x] = s[1023];     // block total
}

__global__ void scan2_k(int* aux, int naux) {
    __shared__ int s[1024];
    int v = (threadIdx.x < naux) ? aux[threadIdx.x] : 0;
    s[threadIdx.x] = v;
    __syncthreads();
    for (int off = 1; off < 1024; off <<= 1) {
        int t = (threadIdx.x >= off) ? s[threadIdx.x - off] : 0;
        __syncthreads();
        s[threadIdx.x] += t;
        __syncthreads();
    }
    if (threadIdx.x < naux) aux[threadIdx.x] = s[threadIdx.x] - v;
}

__global__ void part_scatter_k(const int* __restrict__ src, const int* __restrict__ dst,
                               const int* __restrict__ table, const int* __restrict__ aux,
                               unsigned* __restrict__ packed, int e, int nb) {
    __shared__ int loff[1024];
    for (int k = threadIdx.x; k < nb; k += 256) {
        int idx = k * PB + blockIdx.x;
        loff[k] = table[idx] + aux[idx >> 10];
    }
    __syncthreads();
    int eb = (e + PB - 1) / PB;
    int lo = blockIdx.x * eb, hi = min(lo + eb, e);
    for (int i = lo + threadIdx.x; i < hi; i += 256) {
        int d = dst[i];
        int p = atomicAdd(&loff[d >> BSH], 1);
        packed[p] = ((unsigned)(d & (BNODES - 1)) << 25) | (unsigned)src[i];
    }
}

// ---------------- stage 2: per-bucket counting sort -> per-node CSR + dinv ----

__global__ void bucket_sort_k(const unsigned* __restrict__ packed,
                              const int* __restrict__ table, const int* __restrict__ aux,
                              int* __restrict__ col, int* __restrict__ rowptr,
                              float* __restrict__ dinv, int n, int e, int nb) {
    __shared__ int cnt[BNODES];
    __shared__ int s[BNODES];
    __shared__ int cur[BNODES];
    const int k = blockIdx.x;
    const int t = threadIdx.x;
    if (t < BNODES) cnt[t] = 0;
    __syncthreads();
    int i0 = k * PB;
    int i1 = (k + 1) * PB;
    const int bs = table[i0] + aux[i0 >> 10];
    const int be = (k + 1 < nb) ? (table[i1] + aux[i1 >> 10]) : e;
    for (int i = bs + t; i < be; i += 256)
        atomicAdd(&cnt[packed[i] >> 25], 1);
    __syncthreads();
    if (t < BNODES) s[t] = cnt[t];
    __syncthreads();
    for (int off = 1; off < BNODES; off <<= 1) {
        int v = (t < BNODES && t >= off) ? s[t - off] : 0;
        __syncthreads();
        if (t < BNODES) s[t] += v;
        __syncthreads();
    }
    if (t < BNODES) {
        int base = bs + s[t] - cnt[t];
        cur[t] = base;
        int node = (k << BSH) + t;
        if (node < n) {
            rowptr[node] = base;
            dinv[node] = 1.0f / sqrtf(1.0f + (float)cnt[t]);
            if (node == n - 1) rowptr[n] = base + cnt[t];
        }
    }
    __syncthreads();
    for (int i = bs + t; i < be; i += 256) {
        unsigned u = packed[i];
        int p = atomicAdd(&cur[u >> 25], 1);
        col[p] = (int)(u & SRCM);
    }
}

// ---------------- dense transform: out[n,64] = fp16((X[n,K] @ W[K,64]) * dinv[row]) ----------------

template<int K>
__global__ __launch_bounds__(256, (K == 128) ? 3 : 4)
void gemm_tile_k(const float* __restrict__ X, const float* __restrict__ W,
                 const float* __restrict__ dinv, __half* __restrict__ out, int n) {
    __shared__ float sX[64][K + 4];
    __shared__ float sW[64][64];       // one 64-row slab of W
    const int row0 = blockIdx.x * 64;
    const int t  = threadIdx.x;
    const int tx = t & 15;
    const int ty = t >> 4;
    constexpr int KSH = (K == 128) ? 7 : 6;

    const float* xb = X + (size_t)row0 * K;
#pragma unroll
    for (int it = 0; it < K / 16; ++it) {
        int fl = it * 1024 + t * 4;
        int r  = fl >> KSH;
        int k  = fl & (K - 1);
        float4 v = make_float4(0.f, 0.f, 0.f, 0.f);
        if (row0 + r < n) v = *(const float4*)(xb + fl);
        *(float4*)&sX[r][k] = v;
    }

    float acc[4][4] = {};
#pragma unroll
    for (int ph = 0; ph < K / 64; ++ph) {
        __syncthreads();
#pragma unroll
        for (int it = 0; it < 4; ++it) {
            int fl = it * 1024 + t * 4;
            *(float4*)&sW[fl >> 6][fl & 63] = *(const float4*)(W + ph * 64 * HID + fl);
        }
        __syncthreads();

#pragma unroll 8
        for (int k = 0; k < 64; k += 4) {
            float4 a[4], b[4];
#pragma unroll
            for (int i = 0; i < 4; i++) a[i] = *(float4*)&sX[ty * 4 + i][ph * 64 + k];
#pragma unroll
            for (int j = 0; j < 4; j++) b[j] = *(float4*)&sW[k + j][tx * 4];
#pragma unroll
            for (int i = 0; i < 4; i++) {
                acc[i][0] = fmaf(a[i].x, b[0].x, acc[i][0]);
                acc[i][1] = fmaf(a[i].x, b[0].y, acc[i][1]);
                acc[i][2] = fmaf(a[i].x, b[0].z, acc[i][2]);
                acc[i][3] = fmaf(a[i].x, b[0].w, acc[i][3]);
                acc[i][0] = fmaf(a[i].y, b[1].x, acc[i][0]);
                acc[i][1] = fmaf(a[i].y, b[1].y, acc[i][1]);
                acc[i][2] = fmaf(a[i].y, b[1].z, acc[i][2]);
                acc[i][3] = fmaf(a[i].y, b[1].w, acc[i][3]);
                acc[i][0] = fmaf(a[i].z, b[2].x, acc[i][0]);
                acc[i][1] = fmaf(a[i].z, b[2].y, acc[i][1]);
                acc[i][2] = fmaf(a[i].z, b[2].z, acc[i][2]);
                acc[i][3] = fmaf(a[i].z, b[2].w, acc[i][3]);
                acc[i][0] = fmaf(a[i].w, b[3].x, acc[i][0]);
                acc[i][1] = fmaf(a[i].w, b[3].y, acc[i][1]);
                acc[i][2] = fmaf(a[i].w, b[3].z, acc[i][2]);
                acc[i][3] = fmaf(a[i].w, b[3].w, acc[i][3]);
            }
        }
    }

#pragma unroll
    for (int i = 0; i < 4; i++) {
        int gr = row0 + ty * 4 + i;
        if (gr < n) {
            float sc = dinv[gr];
            union { __half2 h[2]; unsigned long long u; } pk;
            pk.h[0] = __floats2half2_rn(acc[i][0] * sc, acc[i][1] * sc);
            pk.h[1] = __floats2half2_rn(acc[i][2] * sc, acc[i][3] * sc);
            *(unsigned long long*)(out + (size_t)gr * HID + tx * 4) = pk.u;
        }
    }
}

// ---------------- CSR gather aggregation (fused selfloop + bias + relu [+ logits]) ----
// fp16 rows: 64 feats = 128 B = ONE cache line per edge. One node per 32-lane
// half-wave; each lane owns 2 features via __half2 (4 B/lane, 128 B/row request).

template<bool LOGITS>
__global__ void gather_k(const __half* __restrict__ tS, const int* __restrict__ rowptr,
                         const int* __restrict__ col, const float* __restrict__ dinv,
                         const float* __restrict__ b, float* __restrict__ out,
                         const float* __restrict__ Wa, const float* __restrict__ ba,
                         float* __restrict__ logits, int n) {
    int node = (int)((blockIdx.x * (size_t)blockDim.x + threadIdx.x) >> 5);
    int lane = threadIdx.x & 31;
    if (node >= n) return;
    int beg = rowptr[node], end = rowptr[node + 1];
    const __half2* tl = (const __half2*)tS + lane;   // row stride = 32 half2
    float2 acc = __half22float2(tl[node * 32]);      // self-loop term
    int e = beg;
    for (; e + 16 <= end; e += 16) {
        int s[16];
        __half2 v[16];
#pragma unroll
        for (int j = 0; j < 16; j++) s[j] = col[e + j];
#pragma unroll
        for (int j = 0; j < 16; j++) v[j] = tl[s[j] * 32];
        float2 t0 = make_float2(0.f, 0.f), t1 = make_float2(0.f, 0.f);
#pragma unroll
        for (int j = 0; j < 8; j++) {
            float2 f = __half22float2(v[j]);
            t0.x += f.x; t0.y += f.y;
        }
#pragma unroll
        for (int j = 8; j < 16; j++) {
            float2 f = __half22float2(v[j]);
            t1.x += f.x; t1.y += f.y;
        }
        acc.x += t0.x + t1.x;
        acc.y += t0.y + t1.y;
    }
    for (; e + 4 <= end; e += 4) {
        __half2 v0 = tl[col[e] * 32];
        __half2 v1 = tl[col[e + 1] * 32];
        __half2 v2 = tl[col[e + 2] * 32];
        __half2 v3 = tl[col[e + 3] * 32];
        float2 f0 = __half22float2(v0), f1 = __half22float2(v1);
        float2 f2 = __half22float2(v2), f3 = __half22float2(v3);
        acc.x += (f0.x + f1.x) + (f2.x + f3.x);
        acc.y += (f0.y + f1.y) + (f2.y + f3.y);
    }
    for (; e < end; ++e) {
        float2 f = __half22float2(tl[col[e] * 32]);
        acc.x += f.x; acc.y += f.y;
    }
    float d = dinv[node];
    float2 bb = *(const float2*)(b + 2 * lane);
    float h0 = fmaxf(fmaf(d, acc.x, bb.x), 0.0f);
    float h1 = fmaxf(fmaf(d, acc.y, bb.y), 0.0f);
    *(float2*)(out + (size_t)node * HID + 2 * lane) = make_float2(h0, h1);
    if (LOGITS) {
        float2 wa = *(const float2*)(Wa + 2 * lane);
        float p = h0 * wa.x + h1 * wa.y;
#pragma unroll
        for (int off = 16; off > 0; off >>= 1) p += __shfl_down(p, off, 32);
        if (lane == 0) logits[node] = p + ba[0];
    }
}

// ---------------- heads ----------------

__global__ void pool_k(const float* __restrict__ h, const int* __restrict__ batch,
                       float* __restrict__ pooled, float* __restrict__ counts, int n) {
    int lane = threadIdx.x & 63;
    int wave = threadIdx.x >> 6;
    int start = blockIdx.x * 256 + wave * 64;
    int end   = min(start + 64, n);
    if (start >= end) return;
    float acc = 0.0f;
    int curg = -1, cnt = 0;
    for (int i = start; i < end; i++) {
        int g = batch[i];
        if (g != curg) {
            if (curg >= 0) {
                atomicAdd(&pooled[curg * HID + lane], acc);
                if (lane == 0) atomicAdd(&counts[curg], (float)cnt);
            }
            curg = g; acc = 0.0f; cnt = 0;
        }
        acc += h[(size_t)i * HID + lane];
        cnt++;
    }
    atomicAdd(&pooled[curg * HID + lane], acc);
    if (lane == 0) atomicAdd(&counts[curg], (float)cnt);
}

__global__ void value_k(const float* __restrict__ pooled, const float* __restrict__ counts,
                        const float* __restrict__ Wc, const float* __restrict__ bc,
                        float* __restrict__ val, int g) {
    int gw   = (int)((blockIdx.x * (size_t)blockDim.x + threadIdx.x) >> 6);
    int lane = threadIdx.x & 63;
    if (gw >= g) return;
    float cnt = fmaxf(counts[gw], 1.0f);
    float p = (pooled[gw * HID + lane] / cnt) * Wc[lane];
#pragma unroll
    for (int off = 32; off > 0; off >>= 1) p += __shfl_down(p, off);
    if (lane == 0) val[gw] = p + bc[0];
}

extern "C" void kernel_launch(void* const* d_in, const int* in_sizes, int n_in,
                              void* d_out, int out_size, void* d_ws, size_t ws_size,
                              hipStream_t stream) {
    const float* x     = (const float*)d_in[0];
    const int*   ei    = (const int*)d_in[1];
    const int*   batch = (const int*)d_in[2];
    const float* W1    = (const float*)d_in[3];
    const float* b1    = (const float*)d_in[4];
    const float* W2    = (const float*)d_in[5];
    const float* b2    = (const float*)d_in[6];
    const float* Wa    = (const float*)d_in[7];
    const float* ba    = (const float*)d_in[8];
    const float* Wc    = (const float*)d_in[9];
    const float* bc    = (const float*)d_in[10];

    const int n = in_sizes[0] / FEAT;   // 100000
    const int e = in_sizes[1] / 2;      // 1600000
    const int g = out_size - n;         // 64
    const int* src = ei;
    const int* dst = ei + e;

    const int nb = (n + BNODES - 1) >> BSH;   // buckets (782)
    const int L  = nb * PB;                    // offset table length

    // workspace layout (packed aliases bufA: dead before first gemm)
    float*    ws     = (float*)d_ws;
    float*    dinv   = ws;                               // n
    float*    bufA   = dinv + n;                         // n*HID floats of space (tS, used as fp16)
    float*    bufB   = bufA + (size_t)n * HID;           // n*HID  (h, fp32)
    float*    pooled = bufB + (size_t)n * HID;           // g*HID
    float*    counts = pooled + (size_t)g * HID;         // g
    int*      table  = (int*)(counts + g);               // L
    int*      aux    = table + L;                        // 1024
    int*      rowptr = aux + 1024;                       // n+1
    int*      col    = rowptr + n + 1;                   // e
    unsigned* packed = (unsigned*)bufA;                  // e (aliased, transient)
    __half*   tS     = (__half*)bufA;                    // n*HID fp16 (after packed is dead)

    const int B = 256;
    const int gridT = (n + 63) / 64;
    const int gridG = (int)(((size_t)n * 32 + B - 1) / B);   // half-wave per node
    const int nb1   = (L + 1023) / 1024;

    hipMemsetAsync(pooled, 0, (size_t)(g * HID + g) * sizeof(float), stream);

    // two-level CSR build: bucket partition -> in-bucket counting sort
    part_hist_k<<<PB, B, 0, stream>>>(dst, table, e, nb);
    scan1_k<<<nb1, 1024, 0, stream>>>(table, aux, L);
    scan2_k<<<1, 1024, 0, stream>>>(aux, nb1);
    part_scatter_k<<<PB, B, 0, stream>>>(src, dst, table, aux, packed, e, nb);
    bucket_sort_k<<<nb, B, 0, stream>>>(packed, table, aux, col, rowptr, dinv, n, e, nb);

    // layer 1
    gemm_tile_k<FEAT><<<gridT, B, 0, stream>>>(x, W1, dinv, tS, n);
    gather_k<false><<<gridG, B, 0, stream>>>(tS, rowptr, col, dinv, b1, bufB,
                                             nullptr, nullptr, nullptr, n);

    // layer 2 (logits fused into gather epilogue)
    gemm_tile_k<HID><<<gridT, B, 0, stream>>>(bufB, W2, dinv, tS, n);
    gather_k<true><<<gridG, B, 0, stream>>>(tS, rowptr, col, dinv, b2, bufB,
                                            Wa, ba, (float*)d_out, n);

    // heads
    pool_k<<<(n + 255) / 256, B, 0, stream>>>(bufB, batch, pooled, counts, n);
    value_k<<<(g * 64 + B - 1) / B, B, 0, stream>>>(pooled, counts, Wc, bc, (float*)d_out + n, g);
}

// Round 2
// 304.356 us; speedup vs baseline: 1.1914x; 1.0257x over previous
//
#include <hip/hip_runtime.h>
#include <hip/hip_fp16.h>
#include <math.h>

#define FEAT 128
#define HID  64
#define BSH  7                 // 128 dst-nodes per bucket
#define BNODES (1 << BSH)
#define PB   256               // partition blocks (256: full-chip parallelism — PB=64 regressed 2.5x)
#define SRCM ((1u << 25) - 1)  // src in low 25 bits, dst_local in high 7

// ---------------- stage 1: edge partition by dst-bucket ----------------

__global__ void part_hist_k(const int* __restrict__ dst, int* __restrict__ table,
                            int e, int nb) {
    __shared__ int lcnt[1024];
    for (int i = threadIdx.x; i < nb; i += 256) lcnt[i] = 0;
    __syncthreads();
    int eb = (e + PB - 1) / PB;
    int lo = blockIdx.x * eb, hi = min(lo + eb, e);
    for (int i = lo + threadIdx.x; i < hi; i += 256)
        atomicAdd(&lcnt[dst[i] >> BSH], 1);
    __syncthreads();
    for (int k = threadIdx.x; k < nb; k += 256)
        table[k * PB + blockIdx.x] = lcnt[k];
}

__global__ void scan1_k(int* __restrict__ data, int* __restrict__ aux, int L) {
    __shared__ int s[1024];
    int gid = blockIdx.x * 1024 + threadIdx.x;
    int v = (gid < L) ? data[gid] : 0;
    s[threadIdx.x] = v;
    __syncthreads();
    for (int off = 1; off < 1024; off <<= 1) {
        int t = (threadIdx.x >= off) ? s[threadIdx.x - off] : 0;
        __syncthreads();
        s[threadIdx.x] += t;
        __syncthreads();
    }
    if (gid < L) data[gid] = s[threadIdx.x] - v;            // exclusive in block
    if (threadIdx.x == 1023) aux[blockIdx.x] = s[1023];     // block total
}

__global__ void scan2_k(int* aux, int naux) {
    __shared__ int s[1024];
    int v = (threadIdx.x < naux) ? aux[threadIdx.x] : 0;
    s[threadIdx.x] = v;
    __syncthreads();
    for (int off = 1; off < 1024; off <<= 1) {
        int t = (threadIdx.x >= off) ? s[threadIdx.x - off] : 0;
        __syncthreads();
        s[threadIdx.x] += t;
        __syncthreads();
    }
    if (threadIdx.x < naux) aux[threadIdx.x] = s[threadIdx.x] - v;
}

__global__ void part_scatter_k(const int* __restrict__ src, const int* __restrict__ dst,
                               const int* __restrict__ table, const int* __restrict__ aux,
                               unsigned* __restrict__ packed, int e, int nb) {
    __shared__ int loff[1024];
    for (int k = threadIdx.x; k < nb; k += 256) {
        int idx = k * PB + blockIdx.x;
        loff[k] = table[idx] + aux[idx >> 10];
    }
    __syncthreads();
    int eb = (e + PB - 1) / PB;
    int lo = blockIdx.x * eb, hi = min(lo + eb, e);
    for (int i = lo + threadIdx.x; i < hi; i += 256) {
        int d = dst[i];
        int p = atomicAdd(&loff[d >> BSH], 1);
        packed[p] = ((unsigned)(d & (BNODES - 1)) << 25) | (unsigned)src[i];
    }
}

// ---------------- stage 2: per-bucket counting sort -> per-node CSR + dinv ----

__global__ void bucket_sort_k(const unsigned* __restrict__ packed,
                              const int* __restrict__ table, const int* __restrict__ aux,
                              int* __restrict__ col, int* __restrict__ rowptr,
                              float* __restrict__ dinv, int n, int e, int nb) {
    __shared__ int cnt[BNODES];
    __shared__ int s[BNODES];
    __shared__ int cur[BNODES];
    const int k = blockIdx.x;
    const int t = threadIdx.x;
    if (t < BNODES) cnt[t] = 0;
    __syncthreads();
    int i0 = k * PB;
    int i1 = (k + 1) * PB;
    const int bs = table[i0] + aux[i0 >> 10];
    const int be = (k + 1 < nb) ? (table[i1] + aux[i1 >> 10]) : e;
    for (int i = bs + t; i < be; i += 256)
        atomicAdd(&cnt[packed[i] >> 25], 1);
    __syncthreads();
    if (t < BNODES) s[t] = cnt[t];
    __syncthreads();
    for (int off = 1; off < BNODES; off <<= 1) {
        int v = (t < BNODES && t >= off) ? s[t - off] : 0;
        __syncthreads();
        if (t < BNODES) s[t] += v;
        __syncthreads();
    }
    if (t < BNODES) {
        int base = bs + s[t] - cnt[t];
        cur[t] = base;
        int node = (k << BSH) + t;
        if (node < n) {
            rowptr[node] = base;
            dinv[node] = 1.0f / sqrtf(1.0f + (float)cnt[t]);
            if (node == n - 1) rowptr[n] = base + cnt[t];
        }
    }
    __syncthreads();
    for (int i = bs + t; i < be; i += 256) {
        unsigned u = packed[i];
        int p = atomicAdd(&cur[u >> 25], 1);
        col[p] = (int)(u & SRCM);
    }
}

// ---------------- dense transform: out[n,64] = fp16((X[n,K] @ W[K,64]) * dinv[row]) ----
// IN16: input matrix stored fp16 (layer 2 reads gather's fp16 h output)

template<int K, bool IN16>
__global__ __launch_bounds__(256, (K == 128) ? 3 : 4)
void gemm_tile_k(const void* __restrict__ Xv, const float* __restrict__ W,
                 const float* __restrict__ dinv, __half* __restrict__ out, int n) {
    __shared__ float sX[64][K + 4];
    __shared__ float sW[64][64];       // one 64-row slab of W
    const int row0 = blockIdx.x * 64;
    const int t  = threadIdx.x;
    const int tx = t & 15;
    const int ty = t >> 4;
    constexpr int KSH = (K == 128) ? 7 : 6;

    if constexpr (!IN16) {
        const float* xb = (const float*)Xv + (size_t)row0 * K;
#pragma unroll
        for (int it = 0; it < K / 16; ++it) {
            int fl = it * 1024 + t * 4;
            int r  = fl >> KSH;
            int k  = fl & (K - 1);
            float4 v = make_float4(0.f, 0.f, 0.f, 0.f);
            if (row0 + r < n) v = *(const float4*)(xb + fl);
            *(float4*)&sX[r][k] = v;
        }
    } else {
        // fp16 input, K==64: 64x64 halves = 8KB; each thread loads 16 halves (2x16B)
        const __half* xb = (const __half*)Xv + (size_t)row0 * K;
#pragma unroll
        for (int it = 0; it < K / 32; ++it) {
            int fl = it * 2048 + t * 8;    // half-index
            int r  = fl >> KSH;
            int k  = fl & (K - 1);
            float4 raw = make_float4(0.f, 0.f, 0.f, 0.f);
            if (row0 + r < n) raw = *(const float4*)(xb + fl);
            const __half2* hp = (const __half2*)&raw;
#pragma unroll
            for (int j = 0; j < 4; ++j) {
                float2 f = __half22float2(hp[j]);
                sX[r][k + 2 * j]     = f.x;
                sX[r][k + 2 * j + 1] = f.y;
            }
        }
    }

    float acc[4][4] = {};
#pragma unroll
    for (int ph = 0; ph < K / 64; ++ph) {
        __syncthreads();
#pragma unroll
        for (int it = 0; it < 4; ++it) {
            int fl = it * 1024 + t * 4;
            *(float4*)&sW[fl >> 6][fl & 63] = *(const float4*)(W + ph * 64 * HID + fl);
        }
        __syncthreads();

#pragma unroll 8
        for (int k = 0; k < 64; k += 4) {
            float4 a[4], b[4];
#pragma unroll
            for (int i = 0; i < 4; i++) a[i] = *(float4*)&sX[ty * 4 + i][ph * 64 + k];
#pragma unroll
            for (int j = 0; j < 4; j++) b[j] = *(float4*)&sW[k + j][tx * 4];
#pragma unroll
            for (int i = 0; i < 4; i++) {
                acc[i][0] = fmaf(a[i].x, b[0].x, acc[i][0]);
                acc[i][1] = fmaf(a[i].x, b[0].y, acc[i][1]);
                acc[i][2] = fmaf(a[i].x, b[0].z, acc[i][2]);
                acc[i][3] = fmaf(a[i].x, b[0].w, acc[i][3]);
                acc[i][0] = fmaf(a[i].y, b[1].x, acc[i][0]);
                acc[i][1] = fmaf(a[i].y, b[1].y, acc[i][1]);
                acc[i][2] = fmaf(a[i].y, b[1].z, acc[i][2]);
                acc[i][3] = fmaf(a[i].y, b[1].w, acc[i][3]);
                acc[i][0] = fmaf(a[i].z, b[2].x, acc[i][0]);
                acc[i][1] = fmaf(a[i].z, b[2].y, acc[i][1]);
                acc[i][2] = fmaf(a[i].z, b[2].z, acc[i][2]);
                acc[i][3] = fmaf(a[i].z, b[2].w, acc[i][3]);
                acc[i][0] = fmaf(a[i].w, b[3].x, acc[i][0]);
                acc[i][1] = fmaf(a[i].w, b[3].y, acc[i][1]);
                acc[i][2] = fmaf(a[i].w, b[3].z, acc[i][2]);
                acc[i][3] = fmaf(a[i].w, b[3].w, acc[i][3]);
            }
        }
    }

#pragma unroll
    for (int i = 0; i < 4; i++) {
        int gr = row0 + ty * 4 + i;
        if (gr < n) {
            float sc = dinv[gr];
            union { __half2 h[2]; unsigned long long u; } pk;
            pk.h[0] = __floats2half2_rn(acc[i][0] * sc, acc[i][1] * sc);
            pk.h[1] = __floats2half2_rn(acc[i][2] * sc, acc[i][3] * sc);
            *(unsigned long long*)(out + (size_t)gr * HID + tx * 4) = pk.u;
        }
    }
}

// ---------------- CSR gather aggregation ----------------
// fp16 rows: 64 feats = 128 B/row. One node per 32-lane half-wave, lane owns 2
// features (__half2). LOGITS variant fuses: logits head + batch-pooling (block
// LDS partial + one global atomic row; batch is sorted so blocks are almost
// always group-uniform). !LOGITS variant writes h as fp16 for the next GEMM.

template<bool LOGITS>
__global__ void gather_k(const __half* __restrict__ tS, const int* __restrict__ rowptr,
                         const int* __restrict__ col, const float* __restrict__ dinv,
                         const float* __restrict__ b, __half* __restrict__ out,
                         const float* __restrict__ Wa, const float* __restrict__ ba,
                         float* __restrict__ logits, const int* __restrict__ batch,
                         float* __restrict__ pooled, int n) {
    __shared__ float pga[8][64];
    __shared__ int   garr[8];
    int node = (int)((blockIdx.x * (size_t)blockDim.x + threadIdx.x) >> 5);
    int lane = threadIdx.x & 31;
    int w    = threadIdx.x >> 5;
    bool active = node < n;
    if (!LOGITS && !active) return;

    float h0 = 0.f, h1 = 0.f;
    if (active) {
        int beg = rowptr[node], end = rowptr[node + 1];
        const __half2* tl = (const __half2*)tS + lane;   // row stride = 32 half2
        float2 acc = __half22float2(tl[node * 32]);      // self-loop term
        int e = beg;
        for (; e + 16 <= end; e += 16) {
            int s[16];
            __half2 v[16];
#pragma unroll
            for (int j = 0; j < 16; j++) s[j] = col[e + j];
#pragma unroll
            for (int j = 0; j < 16; j++) v[j] = tl[s[j] * 32];
            float2 t0 = make_float2(0.f, 0.f), t1 = make_float2(0.f, 0.f);
#pragma unroll
            for (int j = 0; j < 8; j++) {
                float2 f = __half22float2(v[j]);
                t0.x += f.x; t0.y += f.y;
            }
#pragma unroll
            for (int j = 8; j < 16; j++) {
                float2 f = __half22float2(v[j]);
                t1.x += f.x; t1.y += f.y;
            }
            acc.x += t0.x + t1.x;
            acc.y += t0.y + t1.y;
        }
        for (; e + 4 <= end; e += 4) {
            __half2 v0 = tl[col[e] * 32];
            __half2 v1 = tl[col[e + 1] * 32];
            __half2 v2 = tl[col[e + 2] * 32];
            __half2 v3 = tl[col[e + 3] * 32];
            float2 f0 = __half22float2(v0), f1 = __half22float2(v1);
            float2 f2 = __half22float2(v2), f3 = __half22float2(v3);
            acc.x += (f0.x + f1.x) + (f2.x + f3.x);
            acc.y += (f0.y + f1.y) + (f2.y + f3.y);
        }
        for (; e < end; ++e) {
            float2 f = __half22float2(tl[col[e] * 32]);
            acc.x += f.x; acc.y += f.y;
        }
        float d = dinv[node];
        float2 bb = *(const float2*)(b + 2 * lane);
        h0 = fmaxf(fmaf(d, acc.x, bb.x), 0.0f);
        h1 = fmaxf(fmaf(d, acc.y, bb.y), 0.0f);
        if (!LOGITS) {
            ((__half2*)out)[node * 32 + lane] = __floats2half2_rn(h0, h1);
        } else {
            float2 wa = *(const float2*)(Wa + 2 * lane);
            float p = h0 * wa.x + h1 * wa.y;
#pragma unroll
            for (int off = 16; off > 0; off >>= 1) p += __shfl_down(p, off, 32);
            if (lane == 0) logits[node] = p + ba[0];
        }
    }

    if (LOGITS) {
        // fused mean-pool partial: block = 8 nodes, batch sorted => usually uniform
        *(float2*)&pga[w][2 * lane] = make_float2(active ? h0 : 0.f, active ? h1 : 0.f);
        if (lane == 0) garr[w] = active ? batch[node] : 0x7fffffff;
        __syncthreads();
        int g0 = garr[0];
        bool uniform = true;
#pragma unroll
        for (int i = 1; i < 8; i++) uniform &= (garr[i] == g0 || garr[i] == 0x7fffffff);
        if (uniform) {
            if (threadIdx.x < 64) {
                float s = 0.f;
#pragma unroll
                for (int i = 0; i < 8; i++) s += pga[i][threadIdx.x];
                atomicAdd(&pooled[g0 * HID + threadIdx.x], s);
            }
        } else if (active) {
            int gg = garr[w];
            atomicAdd(&pooled[gg * HID + 2 * lane], h0);
            atomicAdd(&pooled[gg * HID + 2 * lane + 1], h1);
        }
    }
}

// ---------------- value head (counts via binary search on sorted batch) ----------------

__global__ void value_k(const float* __restrict__ pooled, const int* __restrict__ batch,
                        const float* __restrict__ Wc, const float* __restrict__ bc,
                        float* __restrict__ val, int n, int g) {
    int gw   = (int)((blockIdx.x * (size_t)blockDim.x + threadIdx.x) >> 6);
    int lane = threadIdx.x & 63;
    if (gw >= g) return;
    int lo = 0, hi = n;
    while (lo < hi) { int m = (lo + hi) >> 1; if (batch[m] < gw) lo = m + 1; else hi = m; }
    int b0 = lo;
    lo = 0; hi = n;
    while (lo < hi) { int m = (lo + hi) >> 1; if (batch[m] < gw + 1) lo = m + 1; else hi = m; }
    float cnt = fmaxf((float)(lo - b0), 1.0f);
    float p = (pooled[gw * HID + lane] / cnt) * Wc[lane];
#pragma unroll
    for (int off = 32; off > 0; off >>= 1) p += __shfl_down(p, off);
    if (lane == 0) val[gw] = p + bc[0];
}

extern "C" void kernel_launch(void* const* d_in, const int* in_sizes, int n_in,
                              void* d_out, int out_size, void* d_ws, size_t ws_size,
                              hipStream_t stream) {
    const float* x     = (const float*)d_in[0];
    const int*   ei    = (const int*)d_in[1];
    const int*   batch = (const int*)d_in[2];
    const float* W1    = (const float*)d_in[3];
    const float* b1    = (const float*)d_in[4];
    const float* W2    = (const float*)d_in[5];
    const float* b2    = (const float*)d_in[6];
    const float* Wa    = (const float*)d_in[7];
    const float* ba    = (const float*)d_in[8];
    const float* Wc    = (const float*)d_in[9];
    const float* bc    = (const float*)d_in[10];

    const int n = in_sizes[0] / FEAT;   // 100000
    const int e = in_sizes[1] / 2;      // 1600000
    const int g = out_size - n;         // 64
    const int* src = ei;
    const int* dst = ei + e;

    const int nb = (n + BNODES - 1) >> BSH;   // buckets (782)
    const int L  = nb * PB;                    // offset table length

    // workspace layout (packed aliases bufA: dead before first gemm)
    float*    ws     = (float*)d_ws;
    float*    dinv   = ws;                               // n
    float*    bufA   = dinv + n;                         // n*HID floats of space (tS fp16)
    float*    bufB   = bufA + (size_t)n * HID;           // n*HID floats of space (h fp16)
    float*    pooled = bufB + (size_t)n * HID;           // g*HID
    int*      table  = (int*)(pooled + (size_t)g * HID); // L
    int*      aux    = table + L;                        // 1024
    int*      rowptr = aux + 1024;                       // n+1
    int*      col    = rowptr + n + 1;                   // e
    unsigned* packed = (unsigned*)bufA;                  // e (aliased, transient)
    __half*   tS     = (__half*)bufA;                    // n*HID fp16 (after packed dead)
    __half*   h16    = (__half*)bufB;                    // n*HID fp16

    const int B = 256;
    const int gridT = (n + 63) / 64;
    const int gridG = (int)(((size_t)n * 32 + B - 1) / B);   // half-wave per node
    const int nb1   = (L + 1023) / 1024;

    hipMemsetAsync(pooled, 0, (size_t)g * HID * sizeof(float), stream);

    // two-level CSR build: bucket partition -> in-bucket counting sort
    part_hist_k<<<PB, B, 0, stream>>>(dst, table, e, nb);
    scan1_k<<<nb1, 1024, 0, stream>>>(table, aux, L);
    scan2_k<<<1, 1024, 0, stream>>>(aux, nb1);
    part_scatter_k<<<PB, B, 0, stream>>>(src, dst, table, aux, packed, e, nb);
    bucket_sort_k<<<nb, B, 0, stream>>>(packed, table, aux, col, rowptr, dinv, n, e, nb);

    // layer 1
    gemm_tile_k<FEAT, false><<<gridT, B, 0, stream>>>(x, W1, dinv, tS, n);
    gather_k<false><<<gridG, B, 0, stream>>>(tS, rowptr, col, dinv, b1, h16,
                                             nullptr, nullptr, nullptr, nullptr, nullptr, n);

    // layer 2 (logits + mean-pool fused into gather epilogue)
    gemm_tile_k<HID, true><<<gridT, B, 0, stream>>>(h16, W2, dinv, tS, n);
    gather_k<true><<<gridG, B, 0, stream>>>(tS, rowptr, col, dinv, b2, nullptr,
                                            Wa, ba, (float*)d_out, batch, pooled, n);

    // value head
    value_k<<<(g * 64 + B - 1) / B, B, 0, stream>>>(pooled, batch, Wc, bc,
                                                    (float*)d_out + n, n, g);
}